// Round 13
// baseline (1545.992 us; speedup 1.0000x reference)
//
#include <hip/hip_runtime.h>
#include <math.h>

constexpr int Bb  = 64;
constexpr int Tt  = 2048;
constexpr int INN = 128;
constexpr int HH  = 256;
constexpr int ROWS = Bb * Tt;   // 131072
constexpr int CH  = 64;         // pipeline chunk (rows of one batch)
constexpr int NCH = Tt / CH;    // 32 chunks
constexpr int PS  = HH + 4;     // 260: partial-buffer row stride (2-way banks)

typedef float f32x2 __attribute__((ext_vector_type(2)));

// Inter-role progress flags (rows completed per batch). Monotonic within one
// kernel execution; re-zeroed by ih_gemm (previous kernel in stream) each run.
__device__ int g_flag0[Bb];     // producer  -> gemm (rows of h1 done)
__device__ int g_flag1[Bb];     // gemm half 0 -> consumer (its rows done)
__device__ int g_flag1b[Bb];    // gemm half 1 -> consumer

// ---------------------------------------------------------------------------
// Sync fabric (v9/v10/v13-verified): SYSTEM-scope relaxed poll (no
// per-iteration buffer_inv), ONE agent acquire fence after success; agent
// release store; lgkmcnt-only barrier in-chunk, full __syncthreads (vmcnt
// drain) only on the last step before a flag release.
// ---------------------------------------------------------------------------
__device__ __forceinline__ void wait_flag(int* flag, int want)
{
    while (__hip_atomic_load(flag, __ATOMIC_RELAXED,
                             __HIP_MEMORY_SCOPE_SYSTEM) < want)
        __builtin_amdgcn_s_sleep(2);
    __builtin_amdgcn_fence(__ATOMIC_ACQUIRE, "agent");
}

__device__ __forceinline__ void wait_flag2(int* fa, int* fb, int want)
{
    for (;;) {
        int a = __hip_atomic_load(fa, __ATOMIC_RELAXED, __HIP_MEMORY_SCOPE_SYSTEM);
        int c = __hip_atomic_load(fb, __ATOMIC_RELAXED, __HIP_MEMORY_SCOPE_SYSTEM);
        if (a >= want && c >= want) break;
        __builtin_amdgcn_s_sleep(2);
    }
    __builtin_amdgcn_fence(__ATOMIC_ACQUIRE, "agent");
}

__device__ __forceinline__ void release_flag(int* flag, int val)
{
    __hip_atomic_store(flag, val, __ATOMIC_RELEASE, __HIP_MEMORY_SCOPE_AGENT);
}

__device__ __forceinline__ void lds_barrier()
{
    asm volatile("s_waitcnt lgkmcnt(0)" ::: "memory");
    __builtin_amdgcn_s_barrier();
}

// ---------------------------------------------------------------------------
// xp0 GEMM: out[row][j] = sum_k x[row][k]*W[j][k] + b1[j] + b2[j], K=128.
// 256 threads, 64x256 tile, 8x8 per thread (v5-verified machinery).
// Block 0 additionally zeroes the pipeline flags for this run.
// ---------------------------------------------------------------------------
__global__ __launch_bounds__(256) void ih_gemm(const float* in, const float* W,
                                               const float* bias1, const float* bias2,
                                               float* out)
{
    __shared__ float a_lds[16][68];
    __shared__ float b_lds[16][260];

    const int tid = threadIdx.x;
    if (blockIdx.x == 0 && tid < Bb) {
        g_flag0[tid] = 0; g_flag1[tid] = 0; g_flag1b[tid] = 0;
    }

    const int tx  = tid & 31;
    const int ty  = tid >> 5;
    const int row0 = blockIdx.x * 64;

    float acc[8][8];
#pragma unroll
    for (int r = 0; r < 8; ++r)
#pragma unroll
        for (int c = 0; c < 8; ++c) acc[r][c] = 0.f;

    for (int k0 = 0; k0 < INN; k0 += 16) {
#pragma unroll
        for (int i = 0; i < 4; ++i) {
            int e = i * 256 + tid;
            int r = e >> 4, kk = e & 15;
            a_lds[kk][r] = in[(row0 + r) * INN + k0 + kk];
        }
#pragma unroll
        for (int i = 0; i < 16; ++i) {
            int e = i * 256 + tid;
            int j = e >> 4, kk = e & 15;
            b_lds[kk][j] = W[j * INN + k0 + kk];
        }
        __syncthreads();

#pragma unroll
        for (int kk = 0; kk < 16; ++kk) {
            float4 a0 = *(const float4*)&a_lds[kk][ty * 8];
            float4 a1 = *(const float4*)&a_lds[kk][ty * 8 + 4];
            float4 b0 = *(const float4*)&b_lds[kk][tx * 8];
            float4 b1 = *(const float4*)&b_lds[kk][tx * 8 + 4];
            float av[8] = {a0.x, a0.y, a0.z, a0.w, a1.x, a1.y, a1.z, a1.w};
            float bv[8] = {b0.x, b0.y, b0.z, b0.w, b1.x, b1.y, b1.z, b1.w};
#pragma unroll
            for (int r = 0; r < 8; ++r)
#pragma unroll
                for (int c = 0; c < 8; ++c)
                    acc[r][c] += av[r] * bv[c];
        }
        __syncthreads();
    }

    float bsum[8];
#pragma unroll
    for (int c = 0; c < 8; ++c) {
        int j = tx * 8 + c;
        bsum[c] = bias1[j] + bias2[j];
    }
#pragma unroll
    for (int r = 0; r < 8; ++r) {
        int row = row0 + ty * 8 + r;
        float4 o0 = make_float4(acc[r][0] + bsum[0], acc[r][1] + bsum[1],
                                acc[r][2] + bsum[2], acc[r][3] + bsum[3]);
        float4 o1 = make_float4(acc[r][4] + bsum[4], acc[r][5] + bsum[5],
                                acc[r][6] + bsum[6], acc[r][7] + bsum[7]);
        *(float4*)&out[row * HH + tx * 8]     = o0;
        *(float4*)&out[row * HH + tx * 8 + 4] = o1;
    }
}

// ---------------------------------------------------------------------------
// fast tanh, clamp-free: x->+inf: e=inf, rcp=0 -> 1; x->-inf: e=0 -> -1.
// ---------------------------------------------------------------------------
__device__ __forceinline__ float fast_tanh(float x)
{
    float e = __builtin_amdgcn_exp2f(x * 2.8853900817779268f);  // 2*log2(e)
    return fmaf(-2.0f, __builtin_amdgcn_rcpf(e + 1.0f), 1.0f);
}

// fold across lane xor-32: both lanes end with the full sum.
__device__ __forceinline__ float fold32(float s)
{
#if __has_builtin(__builtin_amdgcn_permlane32_swap)
    typedef unsigned uint2v __attribute__((ext_vector_type(2)));
    uint2v r = __builtin_amdgcn_permlane32_swap(__float_as_uint(s), __float_as_uint(s),
                                                false, false);
    return __uint_as_float(r[0]) + __uint_as_float(r[1]);
#else
    return s + __shfl_xor(s, 32, 64);
#endif
}

// ---------------------------------------------------------------------------
// 8-wave layout (512 threads), v10/v13-verified dataflow; MAC packed along
// OUTPUTS (v14): lane l owns outputs 4l..4l+3 as pairs (4l,4l+1),(4l+2,4l+3).
//   w01[c] = {W[4l+0][32w+c], W[4l+1][32w+c]}   (c in [0,32), 64 VGPR)
//   w23[c] = {W[4l+2][32w+c], W[4l+3][32w+c]}   (64 VGPR)
//   MAC: one readlane per c, SPLAT h into both halves -> v_pk_fma_f32 with
//   op_sel-shared scalar (v12's k-pairing needed 2 readlanes + a pack; this
//   needs none). 64 pk_fma replaces 128 fma. Bit-identical sums per output.
//   reduce: output jr = 32w+(l&31); half hf = l>>5 sums sets 4hf..4hf+3
//   (2-way bank alias = free) then ONE fold32. Partial LDS layout unchanged.
// ---------------------------------------------------------------------------
__device__ __forceinline__ void load_wreg(const float* W, int l, int w,
                                          f32x2 (&w01)[32], f32x2 (&w23)[32])
{
#pragma unroll
    for (int q = 0; q < 8; ++q) {
        float4 v0 = *(const float4*)&W[(size_t)(4 * l + 0) * HH + 32 * w + 4 * q];
        float4 v1 = *(const float4*)&W[(size_t)(4 * l + 1) * HH + 32 * w + 4 * q];
        float4 v2 = *(const float4*)&W[(size_t)(4 * l + 2) * HH + 32 * w + 4 * q];
        float4 v3 = *(const float4*)&W[(size_t)(4 * l + 3) * HH + 32 * w + 4 * q];
        w01[4 * q + 0] = f32x2{v0.x, v1.x}; w23[4 * q + 0] = f32x2{v2.x, v3.x};
        w01[4 * q + 1] = f32x2{v0.y, v1.y}; w23[4 * q + 1] = f32x2{v2.y, v3.y};
        w01[4 * q + 2] = f32x2{v0.z, v1.z}; w23[4 * q + 2] = f32x2{v2.z, v3.z};
        w01[4 * q + 3] = f32x2{v0.w, v1.w}; w23[4 * q + 3] = f32x2{v2.w, v3.w};
    }
}

__device__ __forceinline__ void mac_partials(float hv,
                                             const f32x2 (&w01)[32],
                                             const f32x2 (&w23)[32],
                                             float* wr)
{
    f32x2 a01 = {0.f, 0.f}, a23 = {0.f, 0.f};
#pragma unroll
    for (int c = 0; c < 32; ++c) {
        float hcv = __int_as_float(__builtin_amdgcn_readlane(__float_as_int(hv), c));
        f32x2 hs = {hcv, hcv};
        a01 += w01[c] * hs;
        a23 += w23[c] * hs;
    }
    *(float4*)wr = make_float4(a01.x, a01.y, a23.x, a23.y);
}

// One recurrence step, 2-deep xg prefetch ring (xg: step t, xgn: t+1,
// loads t+2). store_h: producer always; consumer only the final step.
template <bool FS>
__device__ __forceinline__ void rnn_step(const float* rd, float* wr,
                                         float*& pw, const float* pr,
                                         float& xg, float& xgn,
                                         const f32x2 (&w01)[32],
                                         const f32x2 (&w23)[32],
                                         bool lane_lt32, bool store_h)
{
    float xg3 = *pr;

    float s0 = rd[0 * PS], s1 = rd[1 * PS], s2 = rd[2 * PS], s3 = rd[3 * PS];
    float s = (s0 + s1) + (s2 + s3);
    s = fold32(s);

    float hv = fast_tanh(s + xg);
    if (store_h && lane_lt32) *pw = hv;

    mac_partials(hv, w01, w23, wr);

    if (FS) __syncthreads(); else lds_barrier();
    xg = xgn; xgn = xg3;
    pw += HH;
}

// ---------------------------------------------------------------------------
// Recurrence role (producer: layer 0 / consumer: layer 1), chunked.
// Consumer discards the cross-chunk prefetches (possibly stale) and
// fresh-loads xg/xgn after the acquire; skips h stores except step Tt-1.
// ---------------------------------------------------------------------------
template <bool PROD>
__device__ void rnn_role(float* xpb, const float* Whh, float* sh, int b)
{
    float* pbufA = sh;
    float* pbufB = sh + 8 * PS;

    const int tid = threadIdx.x;
    const int w   = tid >> 6;            // 0..7
    const int l   = tid & 63;
    const int hf  = l >> 5;              // half: which 4 partial sets
    const int jr  = 32 * w + (l & 31);   // output column this lane finishes
    const bool lane_lt32 = (l < 32);

    f32x2 w01[32], w23[32];
    load_wreg(Whh, l, w, w01, w23);

    const float* rdA = &pbufA[4 * hf * PS + jr];
    const float* rdB = &pbufB[4 * hf * PS + jr];
    float*       wrA = &pbufA[w * PS + 4 * l];
    float*       wrB = &pbufB[w * PS + 4 * l];

    *(float4*)wrA = make_float4(0.f, 0.f, 0.f, 0.f);   // h_{-1} = 0
    float xg  = PROD ? xpb[jr] : 0.f;        // row 0
    float xgn = PROD ? xpb[HH + jr] : 0.f;   // row 1
    float* pw = xpb + jr;
    const float* pr = xpb + 2 * HH + jr;     // prefetch ptr: row 2
    __syncthreads();

#pragma unroll 1
    for (int c = 0; c < NCH; ++c) {
        if (!PROD) {
            wait_flag2(&g_flag1[b], &g_flag1b[b], (c + 1) * (CH / 2));
            const float* rb = xpb + (size_t)c * CH * HH + jr;
            xg = rb[0]; xgn = rb[HH];        // fresh post-acquire
        }
        if (c < NCH - 1) {
#pragma unroll 1
            for (int p = 0; p < CH / 2 - 1; ++p) {
                rnn_step<false>(rdA, wrB, pw, pr, xg, xgn, w01, w23, lane_lt32, PROD); pr += HH;
                rnn_step<false>(rdB, wrA, pw, pr, xg, xgn, w01, w23, lane_lt32, PROD); pr += HH;
            }
            rnn_step<false>(rdA, wrB, pw, pr, xg, xgn, w01, w23, lane_lt32, PROD); pr += HH;
            rnn_step<PROD>(rdB, wrA, pw, pr, xg, xgn, w01, w23, lane_lt32, PROD);  pr += HH;
        } else {
#pragma unroll 1
            for (int p = 0; p < CH / 2 - 1; ++p) {
                rnn_step<false>(rdA, wrB, pw, pr, xg, xgn, w01, w23, lane_lt32, PROD); pr += HH;
                rnn_step<false>(rdB, wrA, pw, pr, xg, xgn, w01, w23, lane_lt32, PROD); pr += HH;
            }
            // final pair: prefetch clamped to row Tt-1 (values discarded).
            // Step Tt-1 stores for BOTH roles (fc reads h2[Tt-1]).
            const float* prc = xpb + (size_t)(Tt - 1) * HH + jr;
            rnn_step<false>(rdA, wrB, pw, prc, xg, xgn, w01, w23, lane_lt32, PROD);
            rnn_step<PROD>(rdB, wrA, pw, prc, xg, xgn, w01, w23, lane_lt32, true);
        }
        if (PROD && tid == 0)
            release_flag(&g_flag0[b], (c + 1) * CH);
    }
}

// ---------------------------------------------------------------------------
// GEMM role (matvec formulation), 2 WGs per batch, half h owns rows
// [32h, 32h+32) of every chunk. Phase p: reduce row p-1 (+bias, store in
// place), MAC row p into the other buffer, one raw barrier. 2-deep prefetch.
// Parity: peeled phase 0 MACs row 0 into B; odd p reads B writes A; even p
// reads A writes B; phase 31 (odd) leaves row 31's partials in A -> the
// tail reduces rdA.
// ---------------------------------------------------------------------------
__device__ __forceinline__ void gemm_phase(const float* rd, float* wr,
                                           float*& pw, const float* pr,
                                           float& xg, float& xgn,
                                           const f32x2 (&w01)[32],
                                           const f32x2 (&w23)[32],
                                           float bsc, bool lane_lt32)
{
    float xg3 = *pr;                 // prefetch row p+2 (clamped at tail)

    float s0 = rd[0 * PS], s1 = rd[1 * PS], s2 = rd[2 * PS], s3 = rd[3 * PS];
    float s = (s0 + s1) + (s2 + s3);
    s = fold32(s);
    if (lane_lt32) *pw = s + bsc;    // commit previous row

    mac_partials(xg, w01, w23, wr);  // partials for current row

    lds_barrier();
    xg = xgn; xgn = xg3;
    pw += HH;
}

__device__ void gemm_role(float* ws, const float* W,
                          const float* b1, const float* b2, float* sh,
                          int b, int half)
{
    float* pbufA = sh;
    float* pbufB = sh + 8 * PS;

    const int tid = threadIdx.x;
    const int w   = tid >> 6;
    const int l   = tid & 63;
    const int hf  = l >> 5;
    const int jr  = 32 * w + (l & 31);
    const bool lane_lt32 = (l < 32);

    f32x2 w01[32], w23[32];
    load_wreg(W, l, w, w01, w23);
    const float bsc = b1[jr] + b2[jr];

    const float* rdA = &pbufA[4 * hf * PS + jr];
    const float* rdB = &pbufB[4 * hf * PS + jr];
    float*       wrA = &pbufA[w * PS + 4 * l];
    float*       wrB = &pbufB[w * PS + 4 * l];

    int* myflag = half ? &g_flag1b[b] : &g_flag1[b];

#pragma unroll 1
    for (int c = 0; c < NCH; ++c) {
        wait_flag(&g_flag0[b], (c + 1) * CH);

        // my 32 rows of this chunk
        float* Ab = ws + ((size_t)b * Tt + (size_t)c * CH + 32 * half) * HH;

        // phase 0 (peeled): MAC row 0 into B, no reduce/store
        float xg  = Ab[jr];                    // fresh post-acquire
        float xgn = Ab[HH + jr];
        const float* pr = Ab + 2 * HH + jr;
        const float* prclamp = Ab + 31 * HH + jr;
        {
            float xg3 = *pr; pr += HH;
            mac_partials(xg, w01, w23, wrB);
            lds_barrier();
            xg = xgn; xgn = xg3;
        }

        float* pw = Ab + jr;                   // store ptr, starts at row 0

        // phases 1..31: phase p reduces row p-1, MACs row p; prefetch row
        // p+2 (clamped to row 31 for p >= 30; clamped values discarded).
#pragma unroll 1
        for (int p = 1; p < 32; ++p) {
            const float* prc = (p <= 29) ? pr : prclamp;
            if (p & 1) gemm_phase(rdB, wrA, pw, prc, xg, xgn, w01, w23, bsc, lane_lt32);
            else       gemm_phase(rdA, wrB, pw, prc, xg, xgn, w01, w23, bsc, lane_lt32);
            pr += HH;
        }

        // tail phase 32: reduce row 31 (partials in A after odd phase 31);
        // FULL sync drains stores before the flag release.
        {
            float s0 = rdA[0 * PS], s1 = rdA[1 * PS];
            float s2 = rdA[2 * PS], s3 = rdA[3 * PS];
            float s = (s0 + s1) + (s2 + s3);
            s = fold32(s);
            if (lane_lt32) *pw = s + bsc;
            __syncthreads();
        }

        if (tid == 0)
            release_flag(myflag, (c + 1) * (CH / 2));
    }
}

// ---------------------------------------------------------------------------
// Pipelined fused kernel, 256 WGs x 512 threads (full chip, 1 WG/CU):
//   blocks 0..63    producer (layer-0 recurrence)
//   blocks 64..191  gemm halves (2 per batch: b = (bid-64)>>1, half = &1)
//   blocks 192..255 consumer (layer-1 recurrence)
// Producers first in blockIdx order; wait graph is a DAG => no deadlock.
// ---------------------------------------------------------------------------
__global__ __launch_bounds__(512, 2) void pipeline_kernel(
        float* ws, const float* Whh0, const float* Wih1,
        const float* bih1, const float* bhh1, const float* Whh1)
{
    __shared__ __attribute__((aligned(16))) float sh[2 * 8 * PS];  // 16640 B

    const int bid = blockIdx.x;

    if (bid < 64) {
        rnn_role<true>(ws + (size_t)bid * Tt * HH, Whh0, sh, bid);
    } else if (bid < 192) {
        const int pidx = bid - 64;
        gemm_role(ws, Wih1, bih1, bhh1, sh, pidx >> 1, pidx & 1);
    } else {
        const int b = bid - 192;
        rnn_role<false>(ws + (size_t)b * Tt * HH, Whh1, sh, b);
    }
}

// ---------------------------------------------------------------------------
// FC: out[b] = dot(h2[b][T-1][:], W_fc) + b_fc.  One wave per batch.
// ---------------------------------------------------------------------------
__global__ __launch_bounds__(64) void fc_kernel(const float* h2, const float* Wfc,
                                                const float* bfc, float* out)
{
    const int b = blockIdx.x;
    const int l = threadIdx.x;
    const float* hrow = h2 + ((size_t)b * Tt + (Tt - 1)) * HH;
    float4 hv = *(const float4*)&hrow[4 * l];
    float4 wv = *(const float4*)&Wfc[4 * l];
    float p = hv.x * wv.x + hv.y * wv.y + hv.z * wv.z + hv.w * wv.w;
#pragma unroll
    for (int off = 32; off > 0; off >>= 1) p += __shfl_down(p, off, 64);
    if (l == 0) out[b] = p + bfc[0];
}

// ---------------------------------------------------------------------------
extern "C" void kernel_launch(void* const* d_in, const int* in_sizes, int n_in,
                              void* d_out, int out_size, void* d_ws, size_t ws_size,
                              hipStream_t stream)
{
    const float* x     = (const float*)d_in[0];
    const float* W_ih0 = (const float*)d_in[1];
    const float* W_hh0 = (const float*)d_in[2];
    const float* b_ih0 = (const float*)d_in[3];
    const float* b_hh0 = (const float*)d_in[4];
    const float* W_ih1 = (const float*)d_in[5];
    const float* W_hh1 = (const float*)d_in[6];
    const float* b_ih1 = (const float*)d_in[7];
    const float* b_hh1 = (const float*)d_in[8];
    const float* W_fc  = (const float*)d_in[9];
    const float* b_fc  = (const float*)d_in[10];
    float* ws  = (float*)d_ws;                 // B*T*H floats (128 MiB)
    float* out = (float*)d_out;

    // 1) xp0 = x @ W_ih0^T + b_ih0 + b_hh0  (+ zero pipeline flags)
    ih_gemm<<<ROWS / 64, 256, 0, stream>>>(x, W_ih0, b_ih0, b_hh0, ws);
    // 2) fused pipeline: L0 recurrence -> chunked xp1 matvec (2 WGs/batch)
    //    -> L1 recurrence, all in-place in ws; ws ends as the h2 sequence.
    pipeline_kernel<<<256, 512, 0, stream>>>(ws, W_hh0, W_ih1, b_ih1, b_hh1, W_hh1);
    // 3) out = h2[:, T-1, :] @ W_fc^T + b_fc
    fc_kernel<<<Bb, 64, 0, stream>>>(ws, W_fc, b_fc, out);
}

// Round 14
// 1431.712 us; speedup vs baseline: 1.0798x; 1.0798x over previous
//
#include <hip/hip_runtime.h>
#include <math.h>

constexpr int Bb  = 64;
constexpr int Tt  = 2048;
constexpr int INN = 128;
constexpr int HH  = 256;
constexpr int ROWS = Bb * Tt;   // 131072
constexpr int CH  = 64;         // pipeline chunk (rows of one batch)
constexpr int NCH = Tt / CH;    // 32 chunks
constexpr int PS  = HH + 4;     // 260: partial-buffer row stride (2-way banks)

// Inter-role progress flags (rows completed per batch). Monotonic within one
// kernel execution; re-zeroed by ih_gemm (previous kernel in stream) each run.
__device__ int g_flag0[Bb];     // producer  -> gemm (rows of h1 done)
__device__ int g_flag1[Bb];     // gemm half 0 -> consumer (its rows done)
__device__ int g_flag1b[Bb];    // gemm half 1 -> consumer

// ---------------------------------------------------------------------------
// Sync fabric (v9/v10/v13-verified): SYSTEM-scope relaxed poll (no
// per-iteration buffer_inv), ONE agent acquire fence after success; agent
// release store; lgkmcnt-only barrier in-chunk, full __syncthreads (vmcnt
// drain) only on the last step before a flag release.
// ---------------------------------------------------------------------------
__device__ __forceinline__ void wait_flag(int* flag, int want)
{
    while (__hip_atomic_load(flag, __ATOMIC_RELAXED,
                             __HIP_MEMORY_SCOPE_SYSTEM) < want)
        __builtin_amdgcn_s_sleep(2);
    __builtin_amdgcn_fence(__ATOMIC_ACQUIRE, "agent");
}

__device__ __forceinline__ void wait_flag2(int* fa, int* fb, int want)
{
    for (;;) {
        int a = __hip_atomic_load(fa, __ATOMIC_RELAXED, __HIP_MEMORY_SCOPE_SYSTEM);
        int c = __hip_atomic_load(fb, __ATOMIC_RELAXED, __HIP_MEMORY_SCOPE_SYSTEM);
        if (a >= want && c >= want) break;
        __builtin_amdgcn_s_sleep(2);
    }
    __builtin_amdgcn_fence(__ATOMIC_ACQUIRE, "agent");
}

__device__ __forceinline__ void release_flag(int* flag, int val)
{
    __hip_atomic_store(flag, val, __ATOMIC_RELEASE, __HIP_MEMORY_SCOPE_AGENT);
}

__device__ __forceinline__ void lds_barrier()
{
    asm volatile("s_waitcnt lgkmcnt(0)" ::: "memory");
    __builtin_amdgcn_s_barrier();
}

// ---------------------------------------------------------------------------
// xp0 GEMM: out[row][j] = sum_k x[row][k]*W[j][k] + b1[j] + b2[j], K=128.
// 256 threads, 64x256 tile, 8x8 per thread (v5-verified machinery).
// Block 0 additionally zeroes the pipeline flags for this run.
// ---------------------------------------------------------------------------
__global__ __launch_bounds__(256) void ih_gemm(const float* in, const float* W,
                                               const float* bias1, const float* bias2,
                                               float* out)
{
    __shared__ float a_lds[16][68];
    __shared__ float b_lds[16][260];

    const int tid = threadIdx.x;
    if (blockIdx.x == 0 && tid < Bb) {
        g_flag0[tid] = 0; g_flag1[tid] = 0; g_flag1b[tid] = 0;
    }

    const int tx  = tid & 31;
    const int ty  = tid >> 5;
    const int row0 = blockIdx.x * 64;

    float acc[8][8];
#pragma unroll
    for (int r = 0; r < 8; ++r)
#pragma unroll
        for (int c = 0; c < 8; ++c) acc[r][c] = 0.f;

    for (int k0 = 0; k0 < INN; k0 += 16) {
#pragma unroll
        for (int i = 0; i < 4; ++i) {
            int e = i * 256 + tid;
            int r = e >> 4, kk = e & 15;
            a_lds[kk][r] = in[(row0 + r) * INN + k0 + kk];
        }
#pragma unroll
        for (int i = 0; i < 16; ++i) {
            int e = i * 256 + tid;
            int j = e >> 4, kk = e & 15;
            b_lds[kk][j] = W[j * INN + k0 + kk];
        }
        __syncthreads();

#pragma unroll
        for (int kk = 0; kk < 16; ++kk) {
            float4 a0 = *(const float4*)&a_lds[kk][ty * 8];
            float4 a1 = *(const float4*)&a_lds[kk][ty * 8 + 4];
            float4 b0 = *(const float4*)&b_lds[kk][tx * 8];
            float4 b1 = *(const float4*)&b_lds[kk][tx * 8 + 4];
            float av[8] = {a0.x, a0.y, a0.z, a0.w, a1.x, a1.y, a1.z, a1.w};
            float bv[8] = {b0.x, b0.y, b0.z, b0.w, b1.x, b1.y, b1.z, b1.w};
#pragma unroll
            for (int r = 0; r < 8; ++r)
#pragma unroll
                for (int c = 0; c < 8; ++c)
                    acc[r][c] += av[r] * bv[c];
        }
        __syncthreads();
    }

    float bsum[8];
#pragma unroll
    for (int c = 0; c < 8; ++c) {
        int j = tx * 8 + c;
        bsum[c] = bias1[j] + bias2[j];
    }
#pragma unroll
    for (int r = 0; r < 8; ++r) {
        int row = row0 + ty * 8 + r;
        float4 o0 = make_float4(acc[r][0] + bsum[0], acc[r][1] + bsum[1],
                                acc[r][2] + bsum[2], acc[r][3] + bsum[3]);
        float4 o1 = make_float4(acc[r][4] + bsum[4], acc[r][5] + bsum[5],
                                acc[r][6] + bsum[6], acc[r][7] + bsum[7]);
        *(float4*)&out[row * HH + tx * 8]     = o0;
        *(float4*)&out[row * HH + tx * 8 + 4] = o1;
    }
}

// ---------------------------------------------------------------------------
// fast tanh, clamp-free: x->+inf: e=inf, rcp=0 -> 1; x->-inf: e=0 -> -1.
// ---------------------------------------------------------------------------
__device__ __forceinline__ float fast_tanh(float x)
{
    float e = __builtin_amdgcn_exp2f(x * 2.8853900817779268f);  // 2*log2(e)
    return fmaf(-2.0f, __builtin_amdgcn_rcpf(e + 1.0f), 1.0f);
}

// fold across lane xor-32: both lanes end with the full sum.
__device__ __forceinline__ float fold32(float s)
{
#if __has_builtin(__builtin_amdgcn_permlane32_swap)
    typedef unsigned uint2v __attribute__((ext_vector_type(2)));
    uint2v r = __builtin_amdgcn_permlane32_swap(__float_as_uint(s), __float_as_uint(s),
                                                false, false);
    return __uint_as_float(r[0]) + __uint_as_float(r[1]);
#else
    return s + __shfl_xor(s, 32, 64);
#endif
}

// ---------------------------------------------------------------------------
// 8-wave layout (512 threads), v10/v13-verified SCALAR MAC (both packed
// f32x2 forms — k-pairing v12, output-pairing v14 — regressed; scalar
// readlane-broadcast fma is the fastest fp32 matvec form on gfx950):
//   wave w (0..7) owns k-chunk [32w, 32w+32); lane l owns outputs 4l..4l+3.
//   wreg[r][c] = W[(4l+r)*HH + 32w + c]  (128 VGPRs, stationary)
//   reduce: output jr = 32w+(l&31); half hf = l>>5 sums sets 4hf..4hf+3
//   (2-way bank alias = free) then ONE fold32.
// ---------------------------------------------------------------------------
__device__ __forceinline__ void load_wreg(const float* W, int l, int w,
                                          float (&wreg)[4][32])
{
#pragma unroll
    for (int r = 0; r < 4; ++r) {
        const float4* wp = (const float4*)&W[(size_t)(4 * l + r) * HH + 32 * w];
#pragma unroll
        for (int q = 0; q < 8; ++q) {
            float4 v = wp[q];
            wreg[r][4 * q + 0] = v.x;
            wreg[r][4 * q + 1] = v.y;
            wreg[r][4 * q + 2] = v.z;
            wreg[r][4 * q + 3] = v.w;
        }
    }
}

__device__ __forceinline__ void mac_partials(float hv, const float (&wreg)[4][32],
                                             float* wr)
{
    float p0 = 0.f, p1 = 0.f, p2 = 0.f, p3 = 0.f;
#pragma unroll
    for (int c = 0; c < 32; ++c) {
        float hcv = __int_as_float(__builtin_amdgcn_readlane(__float_as_int(hv), c));
        p0 = fmaf(wreg[0][c], hcv, p0);
        p1 = fmaf(wreg[1][c], hcv, p1);
        p2 = fmaf(wreg[2][c], hcv, p2);
        p3 = fmaf(wreg[3][c], hcv, p3);
    }
    *(float4*)wr = make_float4(p0, p1, p2, p3);
}

// One recurrence step, 2-deep xg prefetch ring (xg: step t, xgn: t+1,
// loads t+2): the global load is consumed two steps after issue (~3300 cyc
// of cover), so even MALL/HBM-miss latency after an acquire-inv stays off
// the serial chain. store_h: producer always; consumer only the final step
// (h2 is only read at row Tt-1 by fc_kernel).
// ---------------------------------------------------------------------------
template <bool FS>
__device__ __forceinline__ void rnn_step(const float* rd, float* wr,
                                         float*& pw, const float* pr,
                                         float& xg, float& xgn,
                                         const float (&wreg)[4][32],
                                         bool lane_lt32, bool store_h)
{
    float xg3 = *pr;

    float s0 = rd[0 * PS], s1 = rd[1 * PS], s2 = rd[2 * PS], s3 = rd[3 * PS];
    float s = (s0 + s1) + (s2 + s3);
    s = fold32(s);

    float hv = fast_tanh(s + xg);
    if (store_h && lane_lt32) *pw = hv;

    mac_partials(hv, wreg, wr);

    if (FS) __syncthreads(); else lds_barrier();
    xg = xgn; xgn = xg3;
    pw += HH;
}

// ---------------------------------------------------------------------------
// Recurrence role (producer: layer 0 / consumer: layer 1), chunked.
// Consumer discards the cross-chunk prefetches (possibly stale) and
// fresh-loads xg/xgn after the acquire; skips h stores except step Tt-1.
// ---------------------------------------------------------------------------
template <bool PROD>
__device__ void rnn_role(float* xpb, const float* Whh, float* sh, int b)
{
    float* pbufA = sh;
    float* pbufB = sh + 8 * PS;

    const int tid = threadIdx.x;
    const int w   = tid >> 6;            // 0..7
    const int l   = tid & 63;
    const int hf  = l >> 5;              // half: which 4 partial sets
    const int jr  = 32 * w + (l & 31);   // output column this lane finishes
    const bool lane_lt32 = (l < 32);

    float wreg[4][32];
    load_wreg(Whh, l, w, wreg);

    const float* rdA = &pbufA[4 * hf * PS + jr];
    const float* rdB = &pbufB[4 * hf * PS + jr];
    float*       wrA = &pbufA[w * PS + 4 * l];
    float*       wrB = &pbufB[w * PS + 4 * l];

    *(float4*)wrA = make_float4(0.f, 0.f, 0.f, 0.f);   // h_{-1} = 0
    float xg  = PROD ? xpb[jr] : 0.f;        // row 0
    float xgn = PROD ? xpb[HH + jr] : 0.f;   // row 1
    float* pw = xpb + jr;
    const float* pr = xpb + 2 * HH + jr;     // prefetch ptr: row 2
    __syncthreads();

#pragma unroll 1
    for (int c = 0; c < NCH; ++c) {
        if (!PROD) {
            wait_flag2(&g_flag1[b], &g_flag1b[b], (c + 1) * (CH / 2));
            const float* rb = xpb + (size_t)c * CH * HH + jr;
            xg = rb[0]; xgn = rb[HH];        // fresh post-acquire
        }
        if (c < NCH - 1) {
#pragma unroll 1
            for (int p = 0; p < CH / 2 - 1; ++p) {
                rnn_step<false>(rdA, wrB, pw, pr, xg, xgn, wreg, lane_lt32, PROD); pr += HH;
                rnn_step<false>(rdB, wrA, pw, pr, xg, xgn, wreg, lane_lt32, PROD); pr += HH;
            }
            rnn_step<false>(rdA, wrB, pw, pr, xg, xgn, wreg, lane_lt32, PROD); pr += HH;
            rnn_step<PROD>(rdB, wrA, pw, pr, xg, xgn, wreg, lane_lt32, PROD);  pr += HH;
        } else {
#pragma unroll 1
            for (int p = 0; p < CH / 2 - 1; ++p) {
                rnn_step<false>(rdA, wrB, pw, pr, xg, xgn, wreg, lane_lt32, PROD); pr += HH;
                rnn_step<false>(rdB, wrA, pw, pr, xg, xgn, wreg, lane_lt32, PROD); pr += HH;
            }
            // final pair: prefetch clamped to row Tt-1 (values discarded).
            // Step Tt-1 stores for BOTH roles (fc reads h2[Tt-1]).
            const float* prc = xpb + (size_t)(Tt - 1) * HH + jr;
            rnn_step<false>(rdA, wrB, pw, prc, xg, xgn, wreg, lane_lt32, PROD);
            rnn_step<PROD>(rdB, wrA, pw, prc, xg, xgn, wreg, lane_lt32, true);
        }
        if (PROD && tid == 0)
            release_flag(&g_flag0[b], (c + 1) * CH);
    }
}

// ---------------------------------------------------------------------------
// GEMM role (matvec formulation), 2 WGs per batch, half h owns rows
// [32h, 32h+32) of every chunk. Phase p: reduce row p-1 (+bias, store in
// place), MAC row p into the other buffer, one raw barrier. 2-deep prefetch.
// Parity: peeled phase 0 MACs row 0 into B; odd p reads B writes A; even p
// reads A writes B; phase 31 (odd) leaves row 31's partials in A -> the
// tail reduces rdA.
// ---------------------------------------------------------------------------
__device__ __forceinline__ void gemm_phase(const float* rd, float* wr,
                                           float*& pw, const float* pr,
                                           float& xg, float& xgn,
                                           const float (&wreg)[4][32],
                                           float bsc, bool lane_lt32)
{
    float xg3 = *pr;                 // prefetch row p+2 (clamped at tail)

    float s0 = rd[0 * PS], s1 = rd[1 * PS], s2 = rd[2 * PS], s3 = rd[3 * PS];
    float s = (s0 + s1) + (s2 + s3);
    s = fold32(s);
    if (lane_lt32) *pw = s + bsc;    // commit previous row

    mac_partials(xg, wreg, wr);      // partials for current row

    lds_barrier();
    xg = xgn; xgn = xg3;
    pw += HH;
}

__device__ void gemm_role(float* ws, const float* W,
                          const float* b1, const float* b2, float* sh,
                          int b, int half)
{
    float* pbufA = sh;
    float* pbufB = sh + 8 * PS;

    const int tid = threadIdx.x;
    const int w   = tid >> 6;
    const int l   = tid & 63;
    const int hf  = l >> 5;
    const int jr  = 32 * w + (l & 31);
    const bool lane_lt32 = (l < 32);

    float wreg[4][32];
    load_wreg(W, l, w, wreg);
    const float bsc = b1[jr] + b2[jr];

    const float* rdA = &pbufA[4 * hf * PS + jr];
    const float* rdB = &pbufB[4 * hf * PS + jr];
    float*       wrA = &pbufA[w * PS + 4 * l];
    float*       wrB = &pbufB[w * PS + 4 * l];

    int* myflag = half ? &g_flag1b[b] : &g_flag1[b];

#pragma unroll 1
    for (int c = 0; c < NCH; ++c) {
        wait_flag(&g_flag0[b], (c + 1) * CH);

        // my 32 rows of this chunk
        float* Ab = ws + ((size_t)b * Tt + (size_t)c * CH + 32 * half) * HH;

        // phase 0 (peeled): MAC row 0 into B, no reduce/store
        float xg  = Ab[jr];                    // fresh post-acquire
        float xgn = Ab[HH + jr];
        const float* pr = Ab + 2 * HH + jr;
        const float* prclamp = Ab + 31 * HH + jr;
        {
            float xg3 = *pr; pr += HH;
            mac_partials(xg, wreg, wrB);
            lds_barrier();
            xg = xgn; xgn = xg3;
        }

        float* pw = Ab + jr;                   // store ptr, starts at row 0

        // phases 1..31: phase p reduces row p-1, MACs row p; prefetch row
        // p+2 (clamped to row 31 for p >= 30; clamped values discarded).
#pragma unroll 1
        for (int p = 1; p < 32; ++p) {
            const float* prc = (p <= 29) ? pr : prclamp;
            if (p & 1) gemm_phase(rdB, wrA, pw, prc, xg, xgn, wreg, bsc, lane_lt32);
            else       gemm_phase(rdA, wrB, pw, prc, xg, xgn, wreg, bsc, lane_lt32);
            pr += HH;
        }

        // tail phase 32: reduce row 31 (partials in A after odd phase 31);
        // FULL sync drains stores before the flag release.
        {
            float s0 = rdA[0 * PS], s1 = rdA[1 * PS];
            float s2 = rdA[2 * PS], s3 = rdA[3 * PS];
            float s = (s0 + s1) + (s2 + s3);
            s = fold32(s);
            if (lane_lt32) *pw = s + bsc;
            __syncthreads();
        }

        if (tid == 0)
            release_flag(myflag, (c + 1) * (CH / 2));
    }
}

// ---------------------------------------------------------------------------
// Pipelined fused kernel, 256 WGs x 512 threads (full chip, 1 WG/CU):
//   blocks 0..63    producer (layer-0 recurrence)
//   blocks 64..191  gemm halves (2 per batch: b = (bid-64)>>1, half = &1)
//   blocks 192..255 consumer (layer-1 recurrence)
// Producers first in blockIdx order; wait graph is a DAG => no deadlock.
// ---------------------------------------------------------------------------
__global__ __launch_bounds__(512, 2) void pipeline_kernel(
        float* ws, const float* Whh0, const float* Wih1,
        const float* bih1, const float* bhh1, const float* Whh1)
{
    __shared__ __attribute__((aligned(16))) float sh[2 * 8 * PS];  // 16640 B

    const int bid = blockIdx.x;

    if (bid < 64) {
        rnn_role<true>(ws + (size_t)bid * Tt * HH, Whh0, sh, bid);
    } else if (bid < 192) {
        const int pidx = bid - 64;
        gemm_role(ws, Wih1, bih1, bhh1, sh, pidx >> 1, pidx & 1);
    } else {
        const int b = bid - 192;
        rnn_role<false>(ws + (size_t)b * Tt * HH, Whh1, sh, b);
    }
}

// ---------------------------------------------------------------------------
// FC: out[b] = dot(h2[b][T-1][:], W_fc) + b_fc.  One wave per batch.
// ---------------------------------------------------------------------------
__global__ __launch_bounds__(64) void fc_kernel(const float* h2, const float* Wfc,
                                                const float* bfc, float* out)
{
    const int b = blockIdx.x;
    const int l = threadIdx.x;
    const float* hrow = h2 + ((size_t)b * Tt + (Tt - 1)) * HH;
    float4 hv = *(const float4*)&hrow[4 * l];
    float4 wv = *(const float4*)&Wfc[4 * l];
    float p = hv.x * wv.x + hv.y * wv.y + hv.z * wv.z + hv.w * wv.w;
#pragma unroll
    for (int off = 32; off > 0; off >>= 1) p += __shfl_down(p, off, 64);
    if (l == 0) out[b] = p + bfc[0];
}

// ---------------------------------------------------------------------------
extern "C" void kernel_launch(void* const* d_in, const int* in_sizes, int n_in,
                              void* d_out, int out_size, void* d_ws, size_t ws_size,
                              hipStream_t stream)
{
    const float* x     = (const float*)d_in[0];
    const float* W_ih0 = (const float*)d_in[1];
    const float* W_hh0 = (const float*)d_in[2];
    const float* b_ih0 = (const float*)d_in[3];
    const float* b_hh0 = (const float*)d_in[4];
    const float* W_ih1 = (const float*)d_in[5];
    const float* W_hh1 = (const float*)d_in[6];
    const float* b_ih1 = (const float*)d_in[7];
    const float* b_hh1 = (const float*)d_in[8];
    const float* W_fc  = (const float*)d_in[9];
    const float* b_fc  = (const float*)d_in[10];
    float* ws  = (float*)d_ws;                 // B*T*H floats (128 MiB)
    float* out = (float*)d_out;

    // 1) xp0 = x @ W_ih0^T + b_ih0 + b_hh0  (+ zero pipeline flags)
    ih_gemm<<<ROWS / 64, 256, 0, stream>>>(x, W_ih0, b_ih0, b_hh0, ws);
    // 2) fused pipeline: L0 recurrence -> chunked xp1 matvec (2 WGs/batch)
    //    -> L1 recurrence, all in-place in ws; ws ends as the h2 sequence.
    pipeline_kernel<<<256, 512, 0, stream>>>(ws, W_hh0, W_ih1, b_ih1, b_hh1, W_hh1);
    // 3) out = h2[:, T-1, :] @ W_fc^T + b_fc
    fc_kernel<<<Bb, 64, 0, stream>>>(ws, W_fc, b_fc, out);
}